// Round 9
// baseline (225.948 us; speedup 1.0000x reference)
//
#include <hip/hip_runtime.h>
#include <cstdint>
#include <cstddef>

#define EMBED 1024
#define NHEAD 16
#define HD    64
#define BATCH 2
#define SEQ   2048
#define MROWS (BATCH*SEQ)   // 4096
#define QSCALE 0.1803368801111137f   // log2(e)/8

typedef __bf16 bf16;
typedef __bf16 bf16x8 __attribute__((ext_vector_type(8)));
typedef float  f32x4  __attribute__((ext_vector_type(4)));
typedef unsigned int u32;

#if __has_builtin(__builtin_amdgcn_exp2f)
#define EXP2(x) __builtin_amdgcn_exp2f(x)
#else
#define EXP2(x) exp2f(x)
#endif

typedef const u32 __attribute__((address_space(1)))* gp_t;
typedef u32 __attribute__((address_space(3)))* lp_t;

// async global->LDS, 16B/lane; LDS dest = wave-uniform base + lane*16
__device__ __forceinline__ void g2l16(const void* g, void* l) {
  __builtin_amdgcn_global_load_lds((gp_t)(uintptr_t)g, (lp_t)(u32)(uintptr_t)l, 16, 0, 0);
}

#define MFMA(a, b, c) __builtin_amdgcn_mfma_f32_16x16x32_bf16((a), (b), (c), 0, 0, 0)

// ---------------- all casts fp32 -> bf16, one dispatch ----------------
#define SZX8 ((MROWS*EMBED)/8)   // 524288
#define SZW8 ((EMBED*EMBED)/8)   // 131072

__global__ void cast_all(const float* __restrict__ q, const float* __restrict__ k,
                         const float* __restrict__ v, const float* __restrict__ wq,
                         const float* __restrict__ wk, const float* __restrict__ wv,
                         const float* __restrict__ wo,
                         bf16* xq, bf16* xk, bf16* xv,
                         bf16* wqb, bf16* wkb, bf16* wvb, bf16* wob) {
  int z = blockIdx.y;
  const float* in; bf16* out;
  switch (z) {
    case 0: in = q;  out = xq;  break;
    case 1: in = k;  out = xk;  break;
    case 2: in = v;  out = xv;  break;
    case 3: in = wq; out = wqb; break;
    case 4: in = wk; out = wkb; break;
    case 5: in = wv; out = wvb; break;
    default: in = wo; out = wob; break;
  }
  int n8 = (z < 3) ? SZX8 : SZW8;
  int i = blockIdx.x * blockDim.x + threadIdx.x;
  if (i >= n8) return;
  const float4* p = (const float4*)in;
  float4 a = p[2*i], b = p[2*i+1];
  union { bf16 h[8]; uint4 u; } r;
  r.h[0] = (bf16)a.x; r.h[1] = (bf16)a.y; r.h[2] = (bf16)a.z; r.h[3] = (bf16)a.w;
  r.h[4] = (bf16)b.x; r.h[5] = (bf16)b.y; r.h[6] = (bf16)b.z; r.h[7] = (bf16)b.w;
  ((uint4*)out)[i] = r.u;
}

// ---------------- GEMM core 128x128: C = A @ B^T ----------------------
#define BM 128
#define BN 128
#define BK 32
#define NKI (EMBED/BK)   // 32

__device__ __forceinline__ void gemm_core(
    const bf16* __restrict__ A, const bf16* __restrict__ W,
    int m0, int n0, bf16* Al, bf16* Bl, f32x4 (&acc)[4][4])
{
  const int tid  = threadIdx.x;
  const int lane = tid & 63, wid = tid >> 6;
  const int quad = lane >> 4, l16 = lane & 15;
  const int wm = wid >> 1, wn = wid & 1;

  const int R = tid >> 2, Cc = tid & 3;
  const int gcol = (Cc ^ ((R >> 1) & 3)) * 8;          // swizzled source column
  const bf16* Ag = A + (size_t)(m0 + R) * EMBED + gcol;
  const bf16* Bg = W + (size_t)(n0 + R) * EMBED + gcol;
  bf16* AlW = Al + wid * 512;                          // wave's 1KB chunk
  bf16* BlW = Bl + wid * 512;

  g2l16(Ag, AlW);                      g2l16(Ag + (size_t)64*EMBED, AlW + 2048);
  g2l16(Bg, BlW);                      g2l16(Bg + (size_t)64*EMBED, BlW + 2048);
  __syncthreads();

  for (int ki = 0; ki < NKI; ++ki) {
    const int cur = ki & 1;
    if (ki + 1 < NKI) {
      const int nb = cur ^ 1;
      const int k0 = (ki + 1) * BK;
      g2l16(Ag + k0, AlW + nb*4096);
      g2l16(Ag + (size_t)64*EMBED + k0, AlW + nb*4096 + 2048);
      g2l16(Bg + k0, BlW + nb*4096);
      g2l16(Bg + (size_t)64*EMBED + k0, BlW + nb*4096 + 2048);
    }
    const bf16* Ac = Al + cur*4096;
    const bf16* Bc = Bl + cur*4096;
    bf16x8 af[4], bg[4];
#pragma unroll
    for (int i = 0; i < 4; ++i) {
      int ra = wm*64 + i*16 + l16;
      af[i] = *(const bf16x8*)(Ac + ra*32 + ((quad ^ ((ra>>1)&3))*8));
      int rb = wn*64 + i*16 + l16;
      bg[i] = *(const bf16x8*)(Bc + rb*32 + ((quad ^ ((rb>>1)&3))*8));
    }
#pragma unroll
    for (int i = 0; i < 4; ++i)
#pragma unroll
      for (int j = 0; j < 4; ++j)
        acc[i][j] = MFMA(af[i], bg[j], acc[i][j]);
    __syncthreads();
  }
}

// QKV fused: blockIdx.z selects {Q,K,V}. Q scaled by log2(e)/8.
// z==2 computes V^T DIRECTLY: C[dim][token] = Wv @ Xv^T, stored
// pi-permuted per 64-token tile: pos = (loc&15)*4 + (loc>>4).
__global__ __launch_bounds__(256) void qkv_kernel(
    const bf16* __restrict__ Xq, const bf16* __restrict__ Xk, const bf16* __restrict__ Xv,
    const bf16* __restrict__ Wq, const bf16* __restrict__ Wk, const bf16* __restrict__ Wv,
    const float* __restrict__ bq, const float* __restrict__ bk, const float* __restrict__ bv,
    bf16* __restrict__ Qp, bf16* __restrict__ Kp, bf16* __restrict__ VTg)
{
  __shared__ bf16 Al[2*BM*BK];
  __shared__ bf16 Bl[2*BN*BK];
  const int z = blockIdx.z;
  const bf16* A = z==0 ? Xq : z==1 ? Xk : Wv;
  const bf16* W = z==0 ? Wq : z==1 ? Wk : Xv;
  const float* bias = z==0 ? bq : z==1 ? bk : bv;
  const float scale = (z==0) ? QSCALE : 1.0f;
  const int m0 = (z < 2) ? blockIdx.y * BM : blockIdx.x * BM;
  const int n0 = (z < 2) ? blockIdx.x * BN : blockIdx.y * BN;

  f32x4 acc[4][4] = {};
  gemm_core(A, W, m0, n0, Al, Bl, acc);

  const int lane = threadIdx.x & 63, wid = threadIdx.x >> 6;
  const int quad = lane >> 4, l16 = lane & 15;
  const int wm = wid >> 1, wn = wid & 1;

#pragma unroll
  for (int i = 0; i < 4; ++i) {
#pragma unroll
    for (int j = 0; j < 4; ++j) {
      int col = n0 + wn*64 + j*16 + l16;
      if (z < 2) {
        float bv2 = bias[col];
        bf16* outp = (z == 0) ? Qp : Kp;
#pragma unroll
        for (int r = 0; r < 4; ++r) {
          int row = m0 + wm*64 + i*16 + quad*4 + r;
          outp[(size_t)row*EMBED + col] = (bf16)((acc[i][j][r] + bv2) * scale);
        }
      } else {
        int t  = col;
        int bb = t >> 11, ss = t & (SEQ-1);
        int tile = ss >> 6;
        int ppos = l16*4 + (j & 3);   // pi((j&3)*16 + l16)
#pragma unroll
        for (int r = 0; r < 4; ++r) {
          int e = m0 + wm*64 + i*16 + quad*4 + r;
          int hh = e >> 6, dd = e & (HD-1);
          VTg[(((size_t)bb*NHEAD + hh)*HD + dd)*SEQ + tile*64 + ppos]
              = (bf16)(acc[i][j][r] + bias[e]);
        }
      }
    }
  }
}

// ---------------- O-projection: 128x64 tiles, fp32 out ----------------
__global__ __launch_bounds__(256) void oproj_kernel(
    const bf16* __restrict__ Ctx, const bf16* __restrict__ Wo,
    const float* __restrict__ bo, float* __restrict__ out)
{
  __shared__ bf16 Al[2*128*32];   // 2 x 8KB
  __shared__ bf16 Bl[2*64*32];    // 2 x 4KB
  const int tid  = threadIdx.x;
  const int lane = tid & 63, wid = tid >> 6;
  const int quad = lane >> 4, l16 = lane & 15;
  const int m0 = blockIdx.y * 128, n0 = blockIdx.x * 64;

  const int R = tid >> 2, Cc = tid & 3;
  const int gcol = (Cc ^ ((R >> 1) & 3)) * 8;
  const bf16* Ag = Ctx + (size_t)(m0 + R) * EMBED + gcol;
  const bf16* Bg = Wo  + (size_t)(n0 + R) * EMBED + gcol;
  bf16* AlW = Al + wid * 512;
  bf16* BlW = Bl + wid * 512;

  g2l16(Ag, AlW);  g2l16(Ag + (size_t)64*EMBED, AlW + 2048);
  g2l16(Bg, BlW);
  __syncthreads();

  f32x4 acc[2][4] = {};
  for (int ki = 0; ki < NKI; ++ki) {
    const int cur = ki & 1;
    if (ki + 1 < NKI) {
      const int nb = cur ^ 1;
      const int k0 = (ki + 1) * BK;
      g2l16(Ag + k0, AlW + nb*4096);
      g2l16(Ag + (size_t)64*EMBED + k0, AlW + nb*4096 + 2048);
      g2l16(Bg + k0, BlW + nb*2048);
    }
    const bf16* Ac = Al + cur*4096;
    const bf16* Bc = Bl + cur*2048;
    bf16x8 af[2], bg[4];
#pragma unroll
    for (int u = 0; u < 2; ++u) {
      int ra = wid*32 + u*16 + l16;
      af[u] = *(const bf16x8*)(Ac + ra*32 + ((quad ^ ((ra>>1)&3))*8));
    }
#pragma unroll
    for (int j = 0; j < 4; ++j) {
      int rb = j*16 + l16;
      bg[j] = *(const bf16x8*)(Bc + rb*32 + ((quad ^ ((rb>>1)&3))*8));
    }
#pragma unroll
    for (int u = 0; u < 2; ++u)
#pragma unroll
      for (int j = 0; j < 4; ++j)
        acc[u][j] = MFMA(af[u], bg[j], acc[u][j]);
    __syncthreads();
  }

#pragma unroll
  for (int u = 0; u < 2; ++u)
#pragma unroll
    for (int j = 0; j < 4; ++j) {
      int col = n0 + j*16 + l16;
      float bv = bo[col];
#pragma unroll
      for (int r = 0; r < 4; ++r) {
        int row = m0 + wid*32 + u*16 + quad*4 + r;
        out[(size_t)row*EMBED + col] = (acc[u][j][r] + bv);
      }
    }
}

// ---------------- flash attention: pipelined + 32 rows/wave -----------
// 256 threads = 4 waves x 32 q-rows (2 rowgroups); 128-row q-tile;
// grid 512 = 2 blocks/CU. Iteration kt: prefetch K(kt+1), V(kt) |
// QK(kt) | PV(kt-1) | exp+Pwrite(kt). K,V double-buffered (V deferred
// one iter), P (wave-private) double-buffered. Mask as f32 bias table
// in LDS (0 / -1e30), built once — no per-tile global loads.
#define NT  (SEQ/64)
#define PST 72

__global__ __launch_bounds__(256, 2) void attn_kernel(
    const bf16* __restrict__ Qp, const bf16* __restrict__ Kp, const bf16* __restrict__ VT,
    const int* __restrict__ pmask, bf16* __restrict__ Ctx)
{
  __shared__ __align__(16) bf16 Kt[2][64*64];      // 16 KB
  __shared__ __align__(16) bf16 Vt[2][64*64];      // 16 KB
  __shared__ __align__(16) bf16 Pl[2][4][32*PST];  // 36.9 KB
  __shared__ float Mb[SEQ];                        // 8 KB mask bias

  const int qt = blockIdx.x, h = blockIdx.y, b = blockIdx.z;
  const int tid = threadIdx.x, lane = tid & 63, wid = tid >> 6;
  const int quad = lane >> 4, l16 = lane & 15;
  const int qrow0 = qt*128 + wid*32;

  // build mask-bias table: Mb[i] = patch ? 0 : -1e30
  {
    int i = tid * 8;
    const int4* pm4 = (const int4*)(pmask + b*SEQ + i);
    int4 a = pm4[0], c = pm4[1];
    float4 f0, f1;
    f0.x = a.x ? 0.f : -1e30f;  f0.y = a.y ? 0.f : -1e30f;
    f0.z = a.z ? 0.f : -1e30f;  f0.w = a.w ? 0.f : -1e30f;
    f1.x = c.x ? 0.f : -1e30f;  f1.y = c.y ? 0.f : -1e30f;
    f1.z = c.z ? 0.f : -1e30f;  f1.w = c.w ? 0.f : -1e30f;
    *(float4*)(Mb + i)     = f0;
    *(float4*)(Mb + i + 4) = f1;
  }

  bf16x8 qf[2][2];
#pragma unroll
  for (int u = 0; u < 2; ++u) {
    const size_t qoff = (size_t)(b*SEQ + qrow0 + u*16 + l16)*EMBED + h*HD;
    qf[u][0] = *(const bf16x8*)(Qp + qoff + quad*8);
    qf[u][1] = *(const bf16x8*)(Qp + qoff + 32 + quad*8);
  }

  int qm[2][4];
#pragma unroll
  for (int u = 0; u < 2; ++u)
#pragma unroll
    for (int r = 0; r < 4; ++r) qm[u][r] = pmask[b*SEQ + qrow0 + u*16 + quad*4 + r];

  bf16 onev = (bf16)1.0f;
  bf16x8 ones = {onev, onev, onev, onev, onev, onev, onev, onev};

  const bf16* Kg  = Kp + (size_t)b*SEQ*EMBED + h*HD;
  const bf16* VTg = VT + (size_t)(b*NHEAD + h)*HD*SEQ;

  const int R = tid >> 3;                 // 0..31 (key idx for K, dim for V)
  const int Cc = tid & 7;
  const int scol = (Cc ^ (R & 7)) * 8;    // swizzled source column

  f32x4 o[2][4] = {};
  f32x4 lacc[2] = {};

#define STAGE_K(kt, buf) do {                                                \
    const bf16* kg = Kg + (size_t)((kt)*64 + R)*EMBED + scol;                \
    bf16* kl = &Kt[buf][0] + wid*512;                                        \
    g2l16(kg, kl);  g2l16(kg + (size_t)32*EMBED, kl + 2048);                 \
  } while (0)
#define STAGE_V(kt, buf) do {                                                \
    const bf16* vg = VTg + (size_t)R*SEQ + (kt)*64 + scol;                   \
    bf16* vl = &Vt[buf][0] + wid*512;                                        \
    g2l16(vg, vl);  g2l16(vg + (size_t)32*SEQ, vl + 2048);                   \
  } while (0)

  STAGE_K(0, 0);
  __syncthreads();   // mask table + K(0) visible

#pragma unroll 2
  for (int kt = 0; kt < NT; ++kt) {
    const int cur = kt & 1;
    if (kt + 1 < NT) STAGE_K(kt + 1, cur ^ 1);
    STAGE_V(kt, cur);                       // consumed next iteration

    // ---- QK^T(kt): raw scores, K frags shared across both rowgroups ----
    const bf16* Kc = &Kt[cur][0];
    f32x4 sg[2][4];
#pragma unroll
    for (int g = 0; g < 4; ++g) {
      int ra = g*16 + l16, sa = ra & 7;
      bf16x8 kfa = *(const bf16x8*)(Kc + ra*64 + ((quad     ^ sa)*8));
      bf16x8 kfb = *(const bf16x8*)(Kc + ra*64 + (((quad+4) ^ sa)*8));
#pragma unroll
      for (int u = 0; u < 2; ++u) {
        f32x4 s = {};
        s = MFMA(qf[u][0], kfa, s);
        s = MFMA(qf[u][1], kfb, s);
        sg[u][g] = s;
      }
    }

    // ---- PV(kt-1): independent stream ----
    if (kt > 0) {
      const bf16* Vc = &Vt[cur ^ 1][0];
      bf16x8 pf[2][2];
#pragma unroll
      for (int u = 0; u < 2; ++u) {
        const bf16* Pw = &Pl[cur ^ 1][wid][u*16*PST];
        pf[u][0] = *(const bf16x8*)(Pw + l16*PST + quad*8);
        pf[u][1] = *(const bf16x8*)(Pw + l16*PST + 32 + quad*8);
        lacc[u] = MFMA(pf[u][0], ones, lacc[u]);
        lacc[u] = MFMA(pf[u][1], ones, lacc[u]);
      }
#pragma unroll
      for (int t = 0; t < 4; ++t) {
        int rd = t*16 + l16, sd = rd & 7;
        bf16x8 vf0 = *(const bf16x8*)(Vc + rd*64 + ((quad     ^ sd)*8));
        bf16x8 vf1 = *(const bf16x8*)(Vc + rd*64 + (((quad+4) ^ sd)*8));
#pragma unroll
        for (int u = 0; u < 2; ++u) {
          o[u][t] = MFMA(pf[u][0], vf0, o[u][t]);
          o[u][t] = MFMA(pf[u][1], vf1, o[u][t]);
        }
      }
    }

    // ---- mask-bias + exp2 + pi-packed P(kt) store ----
    float bias[4];
#pragma unroll
    for (int g = 0; g < 4; ++g) bias[g] = Mb[kt*64 + g*16 + l16];
#pragma unroll
    for (int u = 0; u < 2; ++u) {
      bf16* Pw = &Pl[cur][wid][u*16*PST];
#pragma unroll
      for (int r = 0; r < 4; ++r) {
        union { bf16 h[4]; uint2 uu; } pk;
#pragma unroll
        for (int g = 0; g < 4; ++g) pk.h[g] = (bf16)EXP2(sg[u][g][r] + bias[g]);
        *(uint2*)(Pw + (quad*4 + r)*PST + l16*4) = pk.uu;
      }
    }
    __syncthreads();   // K(kt+1), V(kt) landed; everyone done with Kt[cur]
  }

  // ---- epilogue PV(NT-1) ----
  {
    const bf16* Vc = &Vt[(NT - 1) & 1][0];
    bf16x8 pf[2][2];
#pragma unroll
    for (int u = 0; u < 2; ++u) {
      const bf16* Pw = &Pl[(NT - 1) & 1][wid][u*16*PST];
      pf[u][0] = *(const bf16x8*)(Pw + l16*PST + quad*8);
      pf[u][1] = *(const bf16x8*)(Pw + l16*PST + 32 + quad*8);
      lacc[u] = MFMA(pf[u][0], ones, lacc[u]);
      lacc[u] = MFMA(pf[u][1], ones, lacc[u]);
    }
#pragma unroll
    for (int t = 0; t < 4; ++t) {
      int rd = t*16 + l16, sd = rd & 7;
      bf16x8 vf0 = *(const bf16x8*)(Vc + rd*64 + ((quad     ^ sd)*8));
      bf16x8 vf1 = *(const bf16x8*)(Vc + rd*64 + (((quad+4) ^ sd)*8));
#pragma unroll
      for (int u = 0; u < 2; ++u) {
        o[u][t] = MFMA(pf[u][0], vf0, o[u][t]);
        o[u][t] = MFMA(pf[u][1], vf1, o[u][t]);
      }
    }
  }

#pragma unroll
  for (int u = 0; u < 2; ++u) {
    float inv[4];
#pragma unroll
    for (int r = 0; r < 4; ++r)
      inv[r] = (qm[u][r] && lacc[u][r] > 0.f) ? 1.0f / lacc[u][r] : 0.0f;
#pragma unroll
    for (int t = 0; t < 4; ++t)
#pragma unroll
      for (int r = 0; r < 4; ++r) {
        int row = b*SEQ + qrow0 + u*16 + quad*4 + r;
        Ctx[(size_t)row*EMBED + h*HD + t*16 + l16] = (bf16)(o[u][t][r] * inv[r]);
      }
  }
}

// ----------------------------------------------------------------------
extern "C" void kernel_launch(void* const* d_in, const int* in_sizes, int n_in,
                              void* d_out, int out_size, void* d_ws, size_t ws_size,
                              hipStream_t stream)
{
  const float* query = (const float*)d_in[0];
  const float* key   = (const float*)d_in[1];
  const float* value = (const float*)d_in[2];
  const int*   pm    = (const int*)d_in[3];
  const float* Wq = (const float*)d_in[4];
  const float* bq = (const float*)d_in[5];
  const float* Wk = (const float*)d_in[6];
  const float* bk = (const float*)d_in[7];
  const float* Wv = (const float*)d_in[8];
  const float* bv = (const float*)d_in[9];
  const float* Wo = (const float*)d_in[10];
  const float* bo = (const float*)d_in[11];
  float* out = (float*)d_out;

  const size_t SZ_X = (size_t)MROWS * EMBED;   // 4M elems
  const size_t SZ_W = (size_t)EMBED * EMBED;   // 1M elems

  bf16* p   = (bf16*)d_ws;
  bf16* Xq  = p; p += SZ_X;
  bf16* Xk  = p; p += SZ_X;
  bf16* Xv  = p; p += SZ_X;
  bf16* Wqb = p; p += SZ_W;
  bf16* Wkb = p; p += SZ_W;
  bf16* Wvb = p; p += SZ_W;
  bf16* Wob = p; p += SZ_W;
  bf16* Qp  = p; p += SZ_X;
  bf16* Kp  = p; p += SZ_X;
  bf16* VTg = p; p += SZ_X;   // V^T: [b][h][d][pi-ordered s]
  bf16* Ctx = p; p += SZ_X;

  dim3 gc((unsigned)(SZX8/256), 7);   // one dispatch for all 7 casts
  cast_all<<<gc, 256, 0, stream>>>(query, key, value, Wq, Wk, Wv, Wo,
                                   Xq, Xk, Xv, Wqb, Wkb, Wvb, Wob);

  dim3 gq(EMBED/BN, MROWS/BM, 3);   // (8, 32, 3)
  qkv_kernel<<<gq, 256, 0, stream>>>(Xq, Xk, Xv, Wqb, Wkb, Wvb, bq, bk, bv, Qp, Kp, VTg);

  dim3 ga(SEQ/128, NHEAD, BATCH);   // (16, 16, 2) = 512 blocks
  attn_kernel<<<ga, 256, 0, stream>>>(Qp, Kp, VTg, pm, Ctx);

  dim3 gg(EMBED/64, MROWS/128);     // (16, 32) = 512 blocks
  oproj_kernel<<<gg, 256, 0, stream>>>(Ctx, Wob, bo, out);
}